// Round 9
// baseline (147.645 us; speedup 1.0000x reference)
//
#include <hip/hip_runtime.h>
#include <math.h>

#define BH   32
#define NSEQ 2048
#define DH   64
#define NH   16
#define LOG2E 1.44269504088896f
#define NJTS 16   // key tiles per split half

typedef _Float16 f16x8 __attribute__((ext_vector_type(8)));
typedef __fp16   fp16x2 __attribute__((ext_vector_type(2)));
typedef _Float16 half2v __attribute__((ext_vector_type(2)));
typedef float    f32x16v __attribute__((ext_vector_type(16)));
typedef unsigned uint2v __attribute__((ext_vector_type(2)));

#if __has_builtin(__builtin_amdgcn_exp2f)
#define EXP2F(x) __builtin_amdgcn_exp2f(x)
#else
#define EXP2F(x) exp2f(x)
#endif

static __device__ __forceinline__ unsigned pkrtz(float a, float b) {
    fp16x2 r = __builtin_amdgcn_cvt_pkrtz(a, b);
    return __builtin_bit_cast(unsigned, r);
}
static __device__ __forceinline__ unsigned packh_rne(float a, float b) {
    union { _Float16 h[2]; unsigned u; } x;
    x.h[0] = (_Float16)a; x.h[1] = (_Float16)b;
    return x.u;
}

// cos/sin of pos * 10000^(-p/32) via revolutions + hw transcendentals
static __device__ __forceinline__ float2 rope_cs(int pos, int p) {
    float invf_rev = EXP2F(-(float)p * (13.287712379549449f / 32.0f)) * 0.15915494309189535f;
    float rev = (float)pos * invf_rev;
    float fr = rev - floorf(rev);
    float th = fr * 6.283185307179586f;
    return make_float2(__cosf(th), __sinf(th));
}

// ---------------- rope table: cos/sin for (pos, dim-pair), computed once -----
__global__ __launch_bounds__(256) void rope_tab_kernel(float4* __restrict__ tab) {
    const int id = blockIdx.x * 256 + threadIdx.x;   // 32768 entries
    const int pos = id >> 4, j = id & 15;
    float2 a = rope_cs(pos, 2 * j);
    float2 b = rope_cs(pos, 2 * j + 1);
    tab[id] = make_float4(a.x, a.y, b.x, b.y);
}

// ---------------- fused prep: q-norm/rope, k-norm/rope (frag-order), v-pack --
// grid.x: [0,2048) q blocks (32 rows), [2048,4096) k blocks, [4096,5120) v tiles.
// K frag order: KF[bh][jt][khw][ks][hf][c][8]; V: VF[bh][jt][kc][rh][hf][c][8].
__global__ __launch_bounds__(256) void prep_all(
    const float* __restrict__ q, const float* __restrict__ k, const float* __restrict__ v,
    const float* __restrict__ qs, const float* __restrict__ ksc,
    const float4* __restrict__ tab,
    unsigned* __restrict__ qh, unsigned* __restrict__ kh, unsigned* __restrict__ vt2) {
    const int bid = blockIdx.x;
    const int t = threadIdx.x;
    if (bid < 4096) {
        const bool isq = bid < 2048;
        const float* in = isq ? q : k;
        const float* sc = isq ? qs : ksc;
        const float smul = isq ? 0.125f * LOG2E : 1.0f;
        const int sb = bid & 2047;
        const int r = t >> 3, l = t & 7;          // row-in-block, lane-in-row
        const int row = sb * 32 + r;
        const int pos = row & (NSEQ - 1);
        const float4* tb = tab + (pos << 4) + 4 * l;
        const float4 c0 = tb[0], c1 = tb[1], c2 = tb[2], c3 = tb[3];
        const float4 xa = *(const float4*)(in + (size_t)row * DH + 8 * l);
        const float4 xb = *(const float4*)(in + (size_t)row * DH + 8 * l + 4);
        float ss = xa.x * xa.x + xa.y * xa.y + xa.z * xa.z + xa.w * xa.w
                 + xb.x * xb.x + xb.y * xb.y + xb.z * xb.z + xb.w * xb.w;
        ss += __shfl_xor(ss, 1);
        ss += __shfl_xor(ss, 2);
        ss += __shfl_xor(ss, 4);
        const float inv = 1.0f / fmaxf(sqrtf(ss), 1e-12f);
        const float4 sa = *(const float4*)(sc + 8 * l);
        const float4 sb4 = *(const float4*)(sc + 8 * l + 4);
        float tv[8];
        tv[0] = xa.x * inv * sa.x;  tv[1] = xa.y * inv * sa.y;
        tv[2] = xa.z * inv * sa.z;  tv[3] = xa.w * inv * sa.w;
        tv[4] = xb.x * inv * sb4.x; tv[5] = xb.y * inv * sb4.y;
        tv[6] = xb.z * inv * sb4.z; tv[7] = xb.w * inv * sb4.w;
        float rv[8];
        #pragma unroll
        for (int e = 0; e < 8; ++e) {
            float p = __shfl_xor(tv[e], 4);
            rv[e] = (l < 4) ? -p : p;
        }
        float ov[8];
        ov[0] = (tv[0] * c0.x + rv[0] * c0.y) * smul;
        ov[1] = (tv[1] * c0.z + rv[1] * c0.w) * smul;
        ov[2] = (tv[2] * c1.x + rv[2] * c1.y) * smul;
        ov[3] = (tv[3] * c1.z + rv[3] * c1.w) * smul;
        ov[4] = (tv[4] * c2.x + rv[4] * c2.y) * smul;
        ov[5] = (tv[5] * c2.z + rv[5] * c2.w) * smul;
        ov[6] = (tv[6] * c3.x + rv[6] * c3.y) * smul;
        ov[7] = (tv[7] * c3.z + rv[7] * c3.w) * smul;
        const uint4 u4 = make_uint4(packh_rne(ov[0], ov[1]), packh_rne(ov[2], ov[3]),
                                    packh_rne(ov[4], ov[5]), packh_rne(ov[6], ov[7]));
        if (isq) {
            *(uint4*)(qh + row * 32 + 4 * l) = u4;
        } else {
            const int rloc = row & (NSEQ - 1);
            const unsigned idx = (unsigned)((rloc >> 5) * 1024 + (l >> 1) * 256
                               + (l & 1) * 128 + (rloc & 31) * 4);
            *(uint4*)(kh + (size_t)(row >> 11) * 65536 + idx) = u4;
        }
    } else {
        // V: fp32 [bh][key][dim] -> frag-order VF via LDS bounce
        const int sb = bid - 4096;
        const int kt = sb & 31, bh = sb >> 5;
        __shared__ float Lv[64 * 68];
        #pragma unroll
        for (int i = 0; i < 4; ++i) {
            int chunk = t + 256 * i;
            int rr = chunk >> 4, fg = chunk & 15;
            *(float4*)&Lv[rr * 68 + fg * 4] =
                *(const float4*)(v + ((size_t)bh * NSEQ + kt * 64 + rr) * DH + fg * 4);
        }
        __syncthreads();
        const int d = t & 63, kg = t >> 6;  // dim, 16-key group
        unsigned u[8];
        #pragma unroll
        for (int j = 0; j < 8; ++j) {
            int ky = kg * 16 + 2 * j;
            u[j] = pkrtz(Lv[ky * 68 + d], Lv[(ky + 1) * 68 + d]);
        }
        const int rh = d >> 5, cc = d & 31;
        unsigned* dst = vt2 + (size_t)bh * 65536
                      + (size_t)((kt * 4 + kg) * 2 + rh) * 256 + cc * 4;
        *(uint4*)(dst)       = make_uint4(u[0], u[1], u[2], u[3]);   // hf=0
        *(uint4*)(dst + 128) = make_uint4(u[4], u[5], u[6], u[7]);   // hf=1
    }
}

// ---------------- shared attn helpers ----------------------------------------
static __device__ __forceinline__ f16x8 ld8(const unsigned* p) {
    return *(const f16x8*)p;
}
static __device__ __forceinline__ void load_k(f16x8 (&kd)[4], const unsigned* p) {
    #pragma unroll
    for (int ks = 0; ks < 4; ++ks) kd[ks] = ld8(p + ks * 256);
}
static __device__ __forceinline__ void load_v(f16x8 (&vd)[4], const unsigned* p) {
    #pragma unroll
    for (int kk = 0; kk < 2; ++kk)
        #pragma unroll
        for (int rh = 0; rh < 2; ++rh)
            vd[kk * 2 + rh] = ld8(p + kk * 512 + rh * 256);
}

// QK for both q-subtiles: 8 INDEPENDENT MFMAs (2 interleaved chains of 4)
static __device__ __forceinline__ void qk2(
    const f16x8 (&kc)[4], const f16x8 (&qf)[2][4], const f32x16v& z16,
    f32x16v& s0, f32x16v& s1)
{
    __builtin_amdgcn_s_setprio(1);
    s0 = __builtin_amdgcn_mfma_f32_32x32x16_f16(kc[0], qf[0][0], z16, 0, 0, 0);
    s1 = __builtin_amdgcn_mfma_f32_32x32x16_f16(kc[0], qf[1][0], z16, 0, 0, 0);
    #pragma unroll
    for (int ks = 1; ks < 4; ++ks) {
        s0 = __builtin_amdgcn_mfma_f32_32x32x16_f16(kc[ks], qf[0][ks], s0, 0, 0, 0);
        s1 = __builtin_amdgcn_mfma_f32_32x32x16_f16(kc[ks], qf[1][ks], s1, 0, 0, 0);
    }
    __builtin_amdgcn_s_setprio(0);
}

// softmax (fixed max; scores bounded by l2norm) + PV for one q-subtile
static __device__ __forceinline__ void pv_tile(
    f32x16v& s, const f16x8 (&vc)[4], f32x16v (&ot)[2], float& lp, int hf)
{
    #pragma unroll
    for (int r = 0; r < 16; ++r) s[r] = EXP2F(s[r]);
    #pragma unroll
    for (int kk = 0; kk < 2; ++kk) {
        unsigned P01 = pkrtz(s[kk * 8 + 0], s[kk * 8 + 1]);
        unsigned P23 = pkrtz(s[kk * 8 + 2], s[kk * 8 + 3]);
        unsigned P45 = pkrtz(s[kk * 8 + 4], s[kk * 8 + 5]);
        unsigned P67 = pkrtz(s[kk * 8 + 6], s[kk * 8 + 7]);
#if __has_builtin(__builtin_amdgcn_fdot2)
        const half2v one2 = {(_Float16)1.0f, (_Float16)1.0f};
        lp = __builtin_amdgcn_fdot2(__builtin_bit_cast(half2v, P01), one2, lp, false);
        lp = __builtin_amdgcn_fdot2(__builtin_bit_cast(half2v, P23), one2, lp, false);
        lp = __builtin_amdgcn_fdot2(__builtin_bit_cast(half2v, P45), one2, lp, false);
        lp = __builtin_amdgcn_fdot2(__builtin_bit_cast(half2v, P67), one2, lp, false);
#else
        #pragma unroll
        for (int r = 0; r < 8; ++r) lp += s[kk * 8 + r];
#endif
        union { unsigned u[4]; f16x8 v; } B;
#if __has_builtin(__builtin_amdgcn_permlane32_swap)
        uint2v r02 = __builtin_amdgcn_permlane32_swap(P01, P45, 0, 0);
        uint2v r13 = __builtin_amdgcn_permlane32_swap(P23, P67, 0, 0);
        B.u[0] = r02[0]; B.u[1] = r13[0]; B.u[2] = r02[1]; B.u[3] = r13[1];
#else
        unsigned x01 = (unsigned)__shfl_xor((int)P01, 32);
        unsigned x23 = (unsigned)__shfl_xor((int)P23, 32);
        unsigned x45 = (unsigned)__shfl_xor((int)P45, 32);
        unsigned x67 = (unsigned)__shfl_xor((int)P67, 32);
        B.u[0] = hf ? x45 : P01;
        B.u[1] = hf ? x67 : P23;
        B.u[2] = hf ? P45 : x01;
        B.u[3] = hf ? P67 : x23;
#endif
        __builtin_amdgcn_s_setprio(1);
        ot[0] = __builtin_amdgcn_mfma_f32_32x32x16_f16(vc[kk * 2 + 0], B.v, ot[0], 0, 0, 0);
        ot[1] = __builtin_amdgcn_mfma_f32_32x32x16_f16(vc[kk * 2 + 1], B.v, ot[1], 0, 0, 0);
        __builtin_amdgcn_s_setprio(0);
    }
}

static __device__ __forceinline__ void smpv2(
    f32x16v& s0, f32x16v& s1, const f16x8 (&vc)[4],
    f32x16v (&o)[2][2], float (&lp)[2], int hf)
{
    pv_tile(s0, vc, o[0], lp[0], hf);
    pv_tile(s1, vc, o[1], lp[1], hf);
}

// ---------------- split attention: key split + interleaved-subtile ILP -------
// grid 1024: bid=(flat<<1)|half. Each WG: 128 q-rows x 16 key tiles (half).
// A/B vs r8: SAME split/TLP (3 waves/SIMD), but the r4-style interleaved body
// (qk2 -> both pv_tile) restores the 8-independent-MFMA QK cluster + 2-chain
// PV ILP that r8's serial qk1->pv removed. Reg budget: acc 64 + s0/s1 32 +
// qf 16 + kc/vc 32 + misc ~20 ~ 164 unified < 170 = 512/3 -> 3 waves/SIMD
// holds. Writes unnormalized O partials + l; merge_kernel combines.
__global__ __launch_bounds__(256, 3) void attn_split(
    const unsigned* __restrict__ qh, const unsigned* __restrict__ kf,
    const unsigned* __restrict__ vf, float* __restrict__ o0buf,
    float* __restrict__ o1buf, float* __restrict__ l0buf,
    float* __restrict__ l1buf) {

    __shared__ float Lred[128 * 33];

    const int bid = blockIdx.x;
    const int h = bid & 1;
    const int rest = bid >> 1;   // 0..511
    const int flat = (rest & 7) * 64 + (rest >> 3);
    const int bh = flat >> 4, qb = flat & 15;

    const int tid = threadIdx.x;
    const int w = tid >> 6, lane = tid & 63;
    const int c = lane & 31, hf = lane >> 5;
    const int qhw = w & 1;
    const int khw = w >> 1;

    const _Float16* qbase = (const _Float16*)qh + ((size_t)bh * NSEQ + qb * 128) * DH;
    f16x8 qf[2][4];
    #pragma unroll
    for (int t = 0; t < 2; ++t)
        #pragma unroll
        for (int ks = 0; ks < 4; ++ks)
            qf[t][ks] = *(const f16x8*)(qbase + (t * 64 + qhw * 32 + c) * DH + ks * 16 + hf * 8);

    const unsigned* kfp = kf + (size_t)bh * 65536 + (size_t)h * NJTS * 2048 + khw * 1024 + lane * 4;
    const unsigned* vfp = vf + (size_t)bh * 65536 + (size_t)h * NJTS * 2048 + khw * 1024 + lane * 4;

    f32x16v z16;
    #pragma unroll
    for (int r = 0; r < 16; ++r) z16[r] = 0.f;

    f32x16v o[2][2];
    #pragma unroll
    for (int t = 0; t < 2; ++t)
        #pragma unroll
        for (int mt = 0; mt < 2; ++mt)
            #pragma unroll
            for (int r = 0; r < 16; ++r) o[t][mt][r] = 0.f;
    float lp[2] = {0.f, 0.f};

    f16x8 kc[4], vc[4];
    load_k(kc, kfp);
    load_v(vc, vfp);

    for (int jt = 0; jt < NJTS; ++jt) {
        f32x16v s0, s1;
        qk2(kc, qf, z16, s0, s1);                        // 8 independent MFMAs
        if (jt + 1 < NJTS) load_k(kc, kfp + (size_t)(jt + 1) * 2048);  // kc dead
        pv_tile(s0, vc, o[0], lp[0], hf);                // SM+PV subtile 0
        pv_tile(s1, vc, o[1], lp[1], hf);                // SM+PV subtile 1
        if (jt + 1 < NJTS) load_v(vc, vfp + (size_t)(jt + 1) * 2048);  // vc dead
    }

    // merge key-half partials across wave pairs (w <-> w+2), write unnormalized
    float lw[2];
    #pragma unroll
    for (int t = 0; t < 2; ++t) lw[t] = lp[t] + __shfl_xor(lp[t], 32);

    const int b = bh >> 4, hh = bh & 15;
    #pragma unroll
    for (int t = 0; t < 2; ++t) {
        if (t) __syncthreads();
        if (w >= 2) {
            const int base = ((w - 2) * 64 + lane) * 33;
            f32x16v* ov = (t == 0) ? &o[0][0] : &o[1][0];
            #pragma unroll
            for (int mt = 0; mt < 2; ++mt)
                #pragma unroll
                for (int r = 0; r < 16; ++r) Lred[base + mt * 16 + r] = ov[mt][r];
            Lred[base + 32] = lw[t];
        }
        __syncthreads();
        if (w < 2) {
            const int base = (w * 64 + lane) * 33;
            f32x16v* ov = (t == 0) ? &o[0][0] : &o[1][0];
            #pragma unroll
            for (int mt = 0; mt < 2; ++mt)
                #pragma unroll
                for (int r = 0; r < 16; ++r) ov[mt][r] += Lred[base + mt * 16 + r];
            const float ltot = lw[t] + Lred[base + 32];
            const int pos = qb * 128 + t * 64 + w * 32 + c;
            float* obase = (h ? o1buf : o0buf)
                         + ((size_t)b * NSEQ + pos) * (NH * DH) + hh * DH;
            #pragma unroll
            for (int mt = 0; mt < 2; ++mt)
                #pragma unroll
                for (int g = 0; g < 4; ++g) {
                    float4 r4 = make_float4(ov[mt][g * 4 + 0], ov[mt][g * 4 + 1],
                                            ov[mt][g * 4 + 2], ov[mt][g * 4 + 3]);
                    *(float4*)(obase + mt * 32 + g * 8 + hf * 4) = r4;
                }
            if (hf == 0) (h ? l1buf : l0buf)[(size_t)bh * NSEQ + pos] = ltot;
        }
    }
}

// ---------------- fallback: r4/r7 single-pass pipelined kernel ---------------
__global__ __launch_bounds__(256, 2) void attn_kernel(
    const unsigned* __restrict__ qh, const unsigned* __restrict__ kf,
    const unsigned* __restrict__ vf, float* __restrict__ out) {

    __shared__ float Lred[128 * 33];

    const int flat = (blockIdx.x & 7) * 64 + (blockIdx.x >> 3);
    const int bh = flat >> 4, qb = flat & 15;

    const int tid = threadIdx.x;
    const int w = tid >> 6, lane = tid & 63;
    const int c = lane & 31, hf = lane >> 5;
    const int qhw = w & 1;
    const int khw = w >> 1;

    const _Float16* qbase = (const _Float16*)qh + ((size_t)bh * NSEQ + qb * 128) * DH;
    f16x8 qf[2][4];
    #pragma unroll
    for (int t = 0; t < 2; ++t)
        #pragma unroll
        for (int ks = 0; ks < 4; ++ks)
            qf[t][ks] = *(const f16x8*)(qbase + (t * 64 + qhw * 32 + c) * DH + ks * 16 + hf * 8);

    const unsigned* kfb = kf + (size_t)bh * 65536 + khw * 1024 + lane * 4;
    const unsigned* vfb = vf + (size_t)bh * 65536 + khw * 1024 + lane * 4;

    f32x16v z16;
    #pragma unroll
    for (int r = 0; r < 16; ++r) z16[r] = 0.f;

    f32x16v o[2][2];
    #pragma unroll
    for (int t = 0; t < 2; ++t)
        #pragma unroll
        for (int mt = 0; mt < 2; ++mt)
            #pragma unroll
            for (int r = 0; r < 16; ++r) o[t][mt][r] = 0.f;
    float lp[2] = {0.f, 0.f};

    f16x8 kc[4], vc[4];
    f32x16v sA0, sA1, sB0, sB1;

    load_k(kc, kfb);
    load_v(vc, vfb);
    qk2(kc, qf, z16, sA0, sA1);
    load_k(kc, kfb + 2048);

    for (int jt = 0; jt < 32; jt += 2) {
        qk2(kc, qf, z16, sB0, sB1);
        if (jt + 2 < 32) load_k(kc, kfb + (size_t)(jt + 2) * 2048);
        smpv2(sA0, sA1, vc, o, lp, hf);
        load_v(vc, vfb + (size_t)(jt + 1) * 2048);

        if (jt + 2 < 32) {
            qk2(kc, qf, z16, sA0, sA1);
            if (jt + 3 < 32) load_k(kc, kfb + (size_t)(jt + 3) * 2048);
        }
        smpv2(sB0, sB1, vc, o, lp, hf);
        if (jt + 2 < 32) load_v(vc, vfb + (size_t)(jt + 2) * 2048);
    }

    float lw[2];
    #pragma unroll
    for (int t = 0; t < 2; ++t) lw[t] = lp[t] + __shfl_xor(lp[t], 32);

    const int b = bh >> 4, h = bh & 15;
    #pragma unroll
    for (int t = 0; t < 2; ++t) {
        if (t) __syncthreads();
        if (w >= 2) {
            const int base = ((w - 2) * 64 + lane) * 33;
            f32x16v* ov = (t == 0) ? &o[0][0] : &o[1][0];
            #pragma unroll
            for (int mt = 0; mt < 2; ++mt)
                #pragma unroll
                for (int r = 0; r < 16; ++r) Lred[base + mt * 16 + r] = ov[mt][r];
            Lred[base + 32] = lw[t];
        }
        __syncthreads();
        if (w < 2) {
            const int base = (w * 64 + lane) * 33;
            f32x16v* ov = (t == 0) ? &o[0][0] : &o[1][0];
            #pragma unroll
            for (int mt = 0; mt < 2; ++mt)
                #pragma unroll
                for (int r = 0; r < 16; ++r) ov[mt][r] += Lred[base + mt * 16 + r];
            float invl = 1.0f / (lw[t] + Lred[base + 32]);
            const int pos = qb * 128 + t * 64 + w * 32 + c;
            float* obase = out + ((size_t)b * NSEQ + pos) * (NH * DH) + h * DH;
            #pragma unroll
            for (int mt = 0; mt < 2; ++mt)
                #pragma unroll
                for (int g = 0; g < 4; ++g) {
                    float4 r4 = make_float4(ov[mt][g * 4 + 0] * invl, ov[mt][g * 4 + 1] * invl,
                                            ov[mt][g * 4 + 2] * invl, ov[mt][g * 4 + 3] * invl);
                    *(float4*)(obase + mt * 32 + g * 8 + hf * 4) = r4;
                }
        }
    }
}

// ---------------- merge: out = (O0 + O1) / (l0 + l1) -------------------------
__global__ __launch_bounds__(256) void merge_kernel(
    float* __restrict__ out, const float* __restrict__ o1,
    const float* __restrict__ l0, const float* __restrict__ l1) {
    const int t = blockIdx.x * 256 + threadIdx.x;
    #pragma unroll
    for (int i = 0; i < 2; ++i) {
        const int f = t + i * 524288;       // float4 index
        const int fi = f * 4;
        const int b  = fi >> 21;
        const int n  = (fi >> 10) & 2047;
        const int hh = (fi >> 6) & 15;
        const int li = ((b << 4) + hh) * NSEQ + n;
        const float inv = 1.0f / (l0[li] + l1[li]);
        float4 a = *(const float4*)(out + fi);
        float4 c = *(const float4*)(o1 + fi);
        *(float4*)(out + fi) = make_float4((a.x + c.x) * inv, (a.y + c.y) * inv,
                                           (a.z + c.z) * inv, (a.w + c.w) * inv);
    }
}

extern "C" void kernel_launch(void* const* d_in, const int* in_sizes, int n_in,
                              void* d_out, int out_size, void* d_ws, size_t ws_size,
                              hipStream_t stream) {
    const float* q  = (const float*)d_in[0];
    const float* k  = (const float*)d_in[1];
    const float* v  = (const float*)d_in[2];
    const float* qs = (const float*)d_in[3];
    const float* ks = (const float*)d_in[4];
    float* outp = (float*)d_out;

    unsigned* qh  = (unsigned*)d_ws;                   // 8 MB
    unsigned* kh  = qh + (size_t)BH * NSEQ * 32;       // 8 MB
    unsigned* vt2 = kh + (size_t)BH * NSEQ * 32;       // 8 MB
    float4*   tab = (float4*)(vt2 + (size_t)BH * NSEQ * 32);   // 512 KB
    float*    pO1 = (float*)(tab + 32768);             // 16 MB (unnorm O, half 1)
    float*    l0  = pO1 + (size_t)2 * NSEQ * NH * DH;  // 256 KB
    float*    l1  = l0 + (size_t)BH * NSEQ;            // 256 KB
    const size_t NEED = (size_t)((char*)(l1 + (size_t)BH * NSEQ) - (char*)d_ws);

    rope_tab_kernel<<<128, 256, 0, stream>>>(tab);
    prep_all<<<5120, 256, 0, stream>>>(q, k, v, qs, ks, tab, qh, kh, vt2);
    if (ws_size >= NEED) {
        attn_split<<<1024, 256, 0, stream>>>(qh, kh, vt2, outp, pO1, l0, l1);
        merge_kernel<<<2048, 256, 0, stream>>>(outp, pO1, l0, l1);
    } else {
        attn_kernel<<<512, 256, 0, stream>>>(qh, kh, vt2, outp);
    }
}

// Round 11
// 137.350 us; speedup vs baseline: 1.0750x; 1.0750x over previous
//
#include <hip/hip_runtime.h>
#include <math.h>

#define BH   32
#define NSEQ 2048
#define DH   64
#define NH   16
#define LOG2E 1.44269504088896f

typedef _Float16 f16x8 __attribute__((ext_vector_type(8)));
typedef __fp16   fp16x2 __attribute__((ext_vector_type(2)));
typedef _Float16 half2v __attribute__((ext_vector_type(2)));
typedef float    f32x16v __attribute__((ext_vector_type(16)));
typedef unsigned uint2v __attribute__((ext_vector_type(2)));

#if __has_builtin(__builtin_amdgcn_exp2f)
#define EXP2F(x) __builtin_amdgcn_exp2f(x)
#else
#define EXP2F(x) exp2f(x)
#endif

static __device__ __forceinline__ unsigned pkrtz(float a, float b) {
    fp16x2 r = __builtin_amdgcn_cvt_pkrtz(a, b);
    return __builtin_bit_cast(unsigned, r);
}
static __device__ __forceinline__ unsigned packh_rne(float a, float b) {
    union { _Float16 h[2]; unsigned u; } x;
    x.h[0] = (_Float16)a; x.h[1] = (_Float16)b;
    return x.u;
}

// cos/sin of pos * 10000^(-p/32) via revolutions + hw transcendentals
static __device__ __forceinline__ float2 rope_cs(int pos, int p) {
    float invf_rev = EXP2F(-(float)p * (13.287712379549449f / 32.0f)) * 0.15915494309189535f;
    float rev = (float)pos * invf_rev;
    float fr = rev - floorf(rev);
    float th = fr * 6.283185307179586f;
    return make_float2(__cosf(th), __sinf(th));
}

// ---------------- rope table: cos/sin for (pos, dim-pair), computed once -----
// tab[pos*16 + j] = (cos(pos,2j), sin(pos,2j), cos(pos,2j+1), sin(pos,2j+1))
__global__ __launch_bounds__(256) void rope_tab_kernel(float4* __restrict__ tab) {
    const int id = blockIdx.x * 256 + threadIdx.x;   // 32768 entries
    const int pos = id >> 4, j = id & 15;
    float2 a = rope_cs(pos, 2 * j);
    float2 b = rope_cs(pos, 2 * j + 1);
    tab[id] = make_float4(a.x, a.y, b.x, b.y);
}

// ---------------- fused prep: q-norm/rope, k-norm/rope (frag-order), v-pack --
// grid.x: [0,2048) q blocks (32 rows), [2048,4096) k blocks, [4096,5120) v tiles.
// q/k: 8 lanes per row, 8 dims per lane (float4x2 in, uint4 out); 3-level
// 8-lane reduce; rotate-half partner = lane^4.
// K frag order: KF[bh][jt][khw][ks][hf][c][8]; V: VF[bh][jt][kc][rh][hf][c][8].
__global__ __launch_bounds__(256) void prep_all(
    const float* __restrict__ q, const float* __restrict__ k, const float* __restrict__ v,
    const float* __restrict__ qs, const float* __restrict__ ksc,
    const float4* __restrict__ tab,
    unsigned* __restrict__ qh, unsigned* __restrict__ kh, unsigned* __restrict__ vt2) {
    const int bid = blockIdx.x;
    const int t = threadIdx.x;
    if (bid < 4096) {
        const bool isq = bid < 2048;
        const float* in = isq ? q : k;
        const float* sc = isq ? qs : ksc;
        const float smul = isq ? 0.125f * LOG2E : 1.0f;
        const int sb = bid & 2047;
        const int r = t >> 3, l = t & 7;          // row-in-block, lane-in-row
        const int row = sb * 32 + r;
        const int pos = row & (NSEQ - 1);
        const float4* tb = tab + (pos << 4) + 4 * l;
        const float4 c0 = tb[0], c1 = tb[1], c2 = tb[2], c3 = tb[3];
        const float4 xa = *(const float4*)(in + (size_t)row * DH + 8 * l);
        const float4 xb = *(const float4*)(in + (size_t)row * DH + 8 * l + 4);
        float ss = xa.x * xa.x + xa.y * xa.y + xa.z * xa.z + xa.w * xa.w
                 + xb.x * xb.x + xb.y * xb.y + xb.z * xb.z + xb.w * xb.w;
        ss += __shfl_xor(ss, 1);
        ss += __shfl_xor(ss, 2);
        ss += __shfl_xor(ss, 4);
        const float inv = 1.0f / fmaxf(sqrtf(ss), 1e-12f);
        const float4 sa = *(const float4*)(sc + 8 * l);
        const float4 sb4 = *(const float4*)(sc + 8 * l + 4);
        float tv[8];
        tv[0] = xa.x * inv * sa.x;  tv[1] = xa.y * inv * sa.y;
        tv[2] = xa.z * inv * sa.z;  tv[3] = xa.w * inv * sa.w;
        tv[4] = xb.x * inv * sb4.x; tv[5] = xb.y * inv * sb4.y;
        tv[6] = xb.z * inv * sb4.z; tv[7] = xb.w * inv * sb4.w;
        // rotate-half: dims 8l+e pair with dims 8(l^4)+e; sign - for d<32 (l<4)
        float rv[8];
        #pragma unroll
        for (int e = 0; e < 8; ++e) {
            float p = __shfl_xor(tv[e], 4);
            rv[e] = (l < 4) ? -p : p;
        }
        float ov[8];
        ov[0] = (tv[0] * c0.x + rv[0] * c0.y) * smul;
        ov[1] = (tv[1] * c0.z + rv[1] * c0.w) * smul;
        ov[2] = (tv[2] * c1.x + rv[2] * c1.y) * smul;
        ov[3] = (tv[3] * c1.z + rv[3] * c1.w) * smul;
        ov[4] = (tv[4] * c2.x + rv[4] * c2.y) * smul;
        ov[5] = (tv[5] * c2.z + rv[5] * c2.w) * smul;
        ov[6] = (tv[6] * c3.x + rv[6] * c3.y) * smul;
        ov[7] = (tv[7] * c3.z + rv[7] * c3.w) * smul;
        const uint4 u4 = make_uint4(packh_rne(ov[0], ov[1]), packh_rne(ov[2], ov[3]),
                                    packh_rne(ov[4], ov[5]), packh_rne(ov[6], ov[7]));
        if (isq) {
            // pair index c = 4l..4l+3 consecutive -> one uint4
            *(uint4*)(qh + row * 32 + 4 * l) = u4;
        } else {
            // frag idx for c=4l+e: (rloc>>5)*1024 + (l>>1)*256 + (l&1)*128
            //                      + (rloc&31)*4 + e  -> e consecutive
            const int rloc = row & (NSEQ - 1);
            const unsigned idx = (unsigned)((rloc >> 5) * 1024 + (l >> 1) * 256
                               + (l & 1) * 128 + (rloc & 31) * 4);
            *(uint4*)(kh + (size_t)(row >> 11) * 65536 + idx) = u4;
        }
    } else {
        // V: fp32 [bh][key][dim] -> frag-order VF via LDS bounce
        const int sb = bid - 4096;
        const int kt = sb & 31, bh = sb >> 5;
        __shared__ float Lv[64 * 68];
        #pragma unroll
        for (int i = 0; i < 4; ++i) {
            int chunk = t + 256 * i;
            int rr = chunk >> 4, fg = chunk & 15;
            *(float4*)&Lv[rr * 68 + fg * 4] =
                *(const float4*)(v + ((size_t)bh * NSEQ + kt * 64 + rr) * DH + fg * 4);
        }
        __syncthreads();
        const int d = t & 63, kg = t >> 6;  // dim, 16-key group
        unsigned u[8];
        #pragma unroll
        for (int j = 0; j < 8; ++j) {
            int ky = kg * 16 + 2 * j;
            u[j] = pkrtz(Lv[ky * 68 + d], Lv[(ky + 1) * 68 + d]);
        }
        const int rh = d >> 5, cc = d & 31;
        unsigned* dst = vt2 + (size_t)bh * 65536
                      + (size_t)((kt * 4 + kg) * 2 + rh) * 256 + cc * 4;
        *(uint4*)(dst)       = make_uint4(u[0], u[1], u[2], u[3]);   // hf=0
        *(uint4*)(dst + 128) = make_uint4(u[4], u[5], u[6], u[7]);   // hf=1
    }
}

// ---------------- flash attention: software-pipelined register streaming -----
// Measured-best configuration (r4/r7: 45.2 us, VGPR 116 arch + 64 acc unified
// -> 2 waves/SIMD). Measured A/Bs that did NOT beat this: 4 waves/SIMD qpt=1
// (r2, 50.4), key-split 3 waves/SIMD serial (r8, 45.7) and interleaved (r9,
// 45.6 + 8us merge overhead), per-WG phase desync (r5, 48.4), launch_bounds
// (256,4) spills accumulators to scratch (r6, 10x regression).
// 4-wave WG covers 128 q-rows; wave w: key-half (w>>1), q-subtiles (w&1)
// rows +0/+64. QK(tile j+1) issues before softmax+PV(tile j). K/V single-
// buffered in regs; s double-buffered. No LDS/barriers in main loop.
static __device__ __forceinline__ f16x8 ld8(const unsigned* p) {
    return *(const f16x8*)p;
}

static __device__ __forceinline__ void load_k(f16x8 (&kd)[4], const unsigned* p) {
    #pragma unroll
    for (int ks = 0; ks < 4; ++ks) kd[ks] = ld8(p + ks * 256);
}
static __device__ __forceinline__ void load_v(f16x8 (&vd)[4], const unsigned* p) {
    #pragma unroll
    for (int kk = 0; kk < 2; ++kk)
        #pragma unroll
        for (int rh = 0; rh < 2; ++rh)
            vd[kk * 2 + rh] = ld8(p + kk * 512 + rh * 256);
}

// QK for both q-subtiles: s0/s1 = K_half * Q^T (results used NEXT step)
static __device__ __forceinline__ void qk2(
    const f16x8 (&kc)[4], const f16x8 (&qf)[2][4], const f32x16v& z16,
    f32x16v& s0, f32x16v& s1)
{
    __builtin_amdgcn_s_setprio(1);
    s0 = __builtin_amdgcn_mfma_f32_32x32x16_f16(kc[0], qf[0][0], z16, 0, 0, 0);
    s1 = __builtin_amdgcn_mfma_f32_32x32x16_f16(kc[0], qf[1][0], z16, 0, 0, 0);
    #pragma unroll
    for (int ks = 1; ks < 4; ++ks) {
        s0 = __builtin_amdgcn_mfma_f32_32x32x16_f16(kc[ks], qf[0][ks], s0, 0, 0, 0);
        s1 = __builtin_amdgcn_mfma_f32_32x32x16_f16(kc[ks], qf[1][ks], s1, 0, 0, 0);
    }
    __builtin_amdgcn_s_setprio(0);
}

// softmax (fixed max; scores bounded by l2norm) + PV for one q-subtile
static __device__ __forceinline__ void pv_tile(
    f32x16v& s, const f16x8 (&vc)[4], f32x16v (&ot)[2], float& lp, int hf)
{
    #pragma unroll
    for (int r = 0; r < 16; ++r) s[r] = EXP2F(s[r]);
    #pragma unroll
    for (int kk = 0; kk < 2; ++kk) {
        unsigned P01 = pkrtz(s[kk * 8 + 0], s[kk * 8 + 1]);
        unsigned P23 = pkrtz(s[kk * 8 + 2], s[kk * 8 + 3]);
        unsigned P45 = pkrtz(s[kk * 8 + 4], s[kk * 8 + 5]);
        unsigned P67 = pkrtz(s[kk * 8 + 6], s[kk * 8 + 7]);
#if __has_builtin(__builtin_amdgcn_fdot2)
        const half2v one2 = {(_Float16)1.0f, (_Float16)1.0f};
        lp = __builtin_amdgcn_fdot2(__builtin_bit_cast(half2v, P01), one2, lp, false);
        lp = __builtin_amdgcn_fdot2(__builtin_bit_cast(half2v, P23), one2, lp, false);
        lp = __builtin_amdgcn_fdot2(__builtin_bit_cast(half2v, P45), one2, lp, false);
        lp = __builtin_amdgcn_fdot2(__builtin_bit_cast(half2v, P67), one2, lp, false);
#else
        #pragma unroll
        for (int r = 0; r < 8; ++r) lp += s[kk * 8 + r];
#endif
        union { unsigned u[4]; f16x8 v; } B;
#if __has_builtin(__builtin_amdgcn_permlane32_swap)
        uint2v r02 = __builtin_amdgcn_permlane32_swap(P01, P45, 0, 0);
        uint2v r13 = __builtin_amdgcn_permlane32_swap(P23, P67, 0, 0);
        B.u[0] = r02[0]; B.u[1] = r13[0]; B.u[2] = r02[1]; B.u[3] = r13[1];
#else
        unsigned x01 = (unsigned)__shfl_xor((int)P01, 32);
        unsigned x23 = (unsigned)__shfl_xor((int)P23, 32);
        unsigned x45 = (unsigned)__shfl_xor((int)P45, 32);
        unsigned x67 = (unsigned)__shfl_xor((int)P67, 32);
        B.u[0] = hf ? x45 : P01;
        B.u[1] = hf ? x67 : P23;
        B.u[2] = hf ? P45 : x01;
        B.u[3] = hf ? P67 : x23;
#endif
        __builtin_amdgcn_s_setprio(1);
        ot[0] = __builtin_amdgcn_mfma_f32_32x32x16_f16(vc[kk * 2 + 0], B.v, ot[0], 0, 0, 0);
        ot[1] = __builtin_amdgcn_mfma_f32_32x32x16_f16(vc[kk * 2 + 1], B.v, ot[1], 0, 0, 0);
        __builtin_amdgcn_s_setprio(0);
    }
}

static __device__ __forceinline__ void smpv2(
    f32x16v& s0, f32x16v& s1, const f16x8 (&vc)[4],
    f32x16v (&o)[2][2], float (&lp)[2], int hf)
{
    pv_tile(s0, vc, o[0], lp[0], hf);
    pv_tile(s1, vc, o[1], lp[1], hf);
}

__global__ __launch_bounds__(256, 2) void attn_kernel(
    const unsigned* __restrict__ qh, const unsigned* __restrict__ kf,
    const unsigned* __restrict__ vf, float* __restrict__ out) {

    __shared__ float Lred[128 * 33];  // 16.9 KB, epilogue merge only

    // bijective XCD-chunked swizzle: XCD x owns flat [x*64,(x+1)*64) = 4 bh
    const int flat = (blockIdx.x & 7) * 64 + (blockIdx.x >> 3);
    const int bh = flat >> 4, qb = flat & 15;   // 16 q-blocks of 128 rows

    const int tid = threadIdx.x;
    const int w = tid >> 6, lane = tid & 63;
    const int c = lane & 31, hf = lane >> 5;
    const int qhw = w & 1;   // 32-row slot within each 64-row half
    const int khw = w >> 1;  // 32-key half of each 64-key tile

    // Q frags (one-time): B[k=dim][n=qrow], two q-subtiles (rows +0 / +64)
    const _Float16* qbase = (const _Float16*)qh + ((size_t)bh * NSEQ + qb * 128) * DH;
    f16x8 qf[2][4];
    #pragma unroll
    for (int t = 0; t < 2; ++t)
        #pragma unroll
        for (int ks = 0; ks < 4; ++ks)
            qf[t][ks] = *(const f16x8*)(qbase + (t * 64 + qhw * 32 + c) * DH + ks * 16 + hf * 8);

    const unsigned* kfb = kf + (size_t)bh * 65536 + khw * 1024 + lane * 4;
    const unsigned* vfb = vf + (size_t)bh * 65536 + khw * 1024 + lane * 4;

    f32x16v z16;
    #pragma unroll
    for (int r = 0; r < 16; ++r) z16[r] = 0.f;

    f32x16v o[2][2];
    #pragma unroll
    for (int t = 0; t < 2; ++t)
        #pragma unroll
        for (int mt = 0; mt < 2; ++mt)
            #pragma unroll
            for (int r = 0; r < 16; ++r) o[t][mt][r] = 0.f;
    float lp[2] = {0.f, 0.f};

    f16x8 kc[4], vc[4];
    f32x16v sA0, sA1, sB0, sB1;

    // prologue: K(0),V(0) -> s(0) ; issue K(1)
    load_k(kc, kfb);
    load_v(vc, vfb);
    qk2(kc, qf, z16, sA0, sA1);          // s(0)
    load_k(kc, kfb + 2048);              // K(1)

    for (int jt = 0; jt < 32; jt += 2) {
        // even step: consume sA=s(jt), V(jt); produce sB=s(jt+1)
        qk2(kc, qf, z16, sB0, sB1);                       // QK(jt+1), uses K(jt+1)
        if (jt + 2 < 32) load_k(kc, kfb + (size_t)(jt + 2) * 2048);
        smpv2(sA0, sA1, vc, o, lp, hf);                   // SM(jt) + PV(V(jt))
        load_v(vc, vfb + (size_t)(jt + 1) * 2048);        // V(jt+1)

        // odd step: consume sB=s(jt+1), V(jt+1); produce sA=s(jt+2)
        if (jt + 2 < 32) {
            qk2(kc, qf, z16, sA0, sA1);                   // QK(jt+2), uses K(jt+2)
            if (jt + 3 < 32) load_k(kc, kfb + (size_t)(jt + 3) * 2048);
        }
        smpv2(sB0, sB1, vc, o, lp, hf);                   // SM(jt+1) + PV(V(jt+1))
        if (jt + 2 < 32) load_v(vc, vfb + (size_t)(jt + 2) * 2048);
    }

    // merge key-half partials across wave pairs (w <-> w+2); two phases reuse
    // the same Lred buffer. stride 33 -> conflict-free.
    float lw[2];
    #pragma unroll
    for (int t = 0; t < 2; ++t) lw[t] = lp[t] + __shfl_xor(lp[t], 32);

    const int b = bh >> 4, h = bh & 15;
    #pragma unroll
    for (int t = 0; t < 2; ++t) {
        if (t) __syncthreads();  // WAR: phase-0 reads done before phase-1 writes
        if (w >= 2) {
            const int base = ((w - 2) * 64 + lane) * 33;
            f32x16v* ov = (t == 0) ? &o[0][0] : &o[1][0];
            #pragma unroll
            for (int mt = 0; mt < 2; ++mt)
                #pragma unroll
                for (int r = 0; r < 16; ++r) Lred[base + mt * 16 + r] = ov[mt][r];
            Lred[base + 32] = lw[t];
        }
        __syncthreads();
        if (w < 2) {
            const int base = (w * 64 + lane) * 33;
            f32x16v* ov = (t == 0) ? &o[0][0] : &o[1][0];
            #pragma unroll
            for (int mt = 0; mt < 2; ++mt)
                #pragma unroll
                for (int r = 0; r < 16; ++r) ov[mt][r] += Lred[base + mt * 16 + r];
            float invl = 1.0f / (lw[t] + Lred[base + 32]);
            const int pos = qb * 128 + t * 64 + w * 32 + c;
            float* obase = out + ((size_t)b * NSEQ + pos) * (NH * DH) + h * DH;
            #pragma unroll
            for (int mt = 0; mt < 2; ++mt)
                #pragma unroll
                for (int g = 0; g < 4; ++g) {
                    float4 r4 = make_float4(ov[mt][g * 4 + 0] * invl, ov[mt][g * 4 + 1] * invl,
                                            ov[mt][g * 4 + 2] * invl, ov[mt][g * 4 + 3] * invl);
                    *(float4*)(obase + mt * 32 + g * 8 + hf * 4) = r4;
                }
        }
    }
}

extern "C" void kernel_launch(void* const* d_in, const int* in_sizes, int n_in,
                              void* d_out, int out_size, void* d_ws, size_t ws_size,
                              hipStream_t stream) {
    const float* q  = (const float*)d_in[0];
    const float* k  = (const float*)d_in[1];
    const float* v  = (const float*)d_in[2];
    const float* qs = (const float*)d_in[3];
    const float* ks = (const float*)d_in[4];
    float* outp = (float*)d_out;

    unsigned* qh  = (unsigned*)d_ws;                   // 8 MB
    unsigned* kh  = qh + (size_t)BH * NSEQ * 32;       // 8 MB
    unsigned* vt2 = kh + (size_t)BH * NSEQ * 32;       // 8 MB
    float4*   tab = (float4*)(vt2 + (size_t)BH * NSEQ * 32);   // 512 KB

    rope_tab_kernel<<<128, 256, 0, stream>>>(tab);
    prep_all<<<5120, 256, 0, stream>>>(q, k, v, qs, ks, tab, qh, kh, vt2);
    attn_kernel<<<512, 256, 0, stream>>>(qh, kh, vt2, outp);
}